// Round 8
// baseline (406.619 us; speedup 1.0000x reference)
//
#include <hip/hip_runtime.h>
#include <math.h>

#define IN_DIM 512
#define EMBED 128
#define OUT_DIM 64
#define NBPAD 256      // padded bucket count (actual NB = ceil(N/256) = 196)
#define SEGSH 12       // 4096 edges per bin block
#define CAP_LDS 10240  // build LDS capacity (mean 8430, +19 sigma)

typedef __attribute__((ext_vector_type(8))) short bf16x8;
typedef __attribute__((ext_vector_type(4))) float f32x4;

__device__ __forceinline__ float lrelu(float v, float s) { return v > 0.f ? v : v * s; }

__device__ __forceinline__ float readlane_f(float v, int l) {
  return __int_as_float(__builtin_amdgcn_readlane(__float_as_int(v), l));
}

__device__ __forceinline__ unsigned short f2bf(float f) {
  unsigned int u = __float_as_uint(f);
  u += 0x7fff + ((u >> 16) & 1);  // RTNE
  return (unsigned short)(u >> 16);
}
__device__ __forceinline__ float bf2f(unsigned short h) {
  return __uint_as_float(((unsigned int)h) << 16);
}

#define LDA 40  // bf16 LDS stride: b128 frag reads 2-way aliased = free (m136)

// ---------------------------------------------------------------------------
// K1 (MFMA split-bf16): h = leaky_relu(x @ Wd^T + bd, 0.01)
// ---------------------------------------------------------------------------
__global__ __launch_bounds__(256) void gemm1_mfma_kernel(
    const float* __restrict__ x, const float* __restrict__ Wd,
    const float* __restrict__ bd, float* __restrict__ h, int N) {
  __shared__ __align__(16) unsigned short Ah[128][LDA];
  __shared__ __align__(16) unsigned short Al[128][LDA];
  __shared__ __align__(16) unsigned short Bh[64][LDA];
  __shared__ __align__(16) unsigned short Bl[64][LDA];

  const int tid = threadIdx.x;
  const int lane = tid & 63;
  const int wid = tid >> 6;
  const int wr = wid >> 1, wc = wid & 1;
  const int mblk = blockIdx.x * 128;
  const int nblk = blockIdx.y * 64;
  const int quad = lane >> 4;
  const int l15 = lane & 15;

  const int arow = tid >> 1, acb = (tid & 1) * 16;
  const int brow = tid >> 2, bcb = (tid & 3) * 8;
  const bool avalid = (mblk + arow) < N;
  const float* aptr = x + (size_t)(mblk + arow) * IN_DIM + acb;
  const float* bptr = Wd + (size_t)(nblk + brow) * IN_DIM + bcb;

  f32x4 acc[4][2];
#pragma unroll
  for (int i = 0; i < 4; ++i)
#pragma unroll
    for (int j = 0; j < 2; ++j) acc[i][j] = (f32x4){0.f, 0.f, 0.f, 0.f};

  for (int k0 = 0; k0 < IN_DIM; k0 += 32) {
    float4 t0, t1, t2, t3;
    if (avalid) {
      t0 = *(const float4*)(aptr + k0);
      t1 = *(const float4*)(aptr + k0 + 4);
      t2 = *(const float4*)(aptr + k0 + 8);
      t3 = *(const float4*)(aptr + k0 + 12);
    } else {
      t0 = t1 = t2 = t3 = make_float4(0.f, 0.f, 0.f, 0.f);
    }
    float4 u0 = *(const float4*)(bptr + k0);
    float4 u1 = *(const float4*)(bptr + k0 + 4);

    float av[16] = {t0.x, t0.y, t0.z, t0.w, t1.x, t1.y, t1.z, t1.w,
                    t2.x, t2.y, t2.z, t2.w, t3.x, t3.y, t3.z, t3.w};
    union { unsigned short us[16]; uint4 v[2]; } AH, AL;
#pragma unroll
    for (int i = 0; i < 16; ++i) {
      unsigned short hi = f2bf(av[i]);
      AH.us[i] = hi;
      AL.us[i] = f2bf(av[i] - bf2f(hi));
    }
    float bv[8] = {u0.x, u0.y, u0.z, u0.w, u1.x, u1.y, u1.z, u1.w};
    union { unsigned short us[8]; uint4 v; } BH, BL;
#pragma unroll
    for (int i = 0; i < 8; ++i) {
      unsigned short hi = f2bf(bv[i]);
      BH.us[i] = hi;
      BL.us[i] = f2bf(bv[i] - bf2f(hi));
    }

    __syncthreads();
    *(uint4*)&Ah[arow][acb] = AH.v[0];
    *(uint4*)&Ah[arow][acb + 8] = AH.v[1];
    *(uint4*)&Al[arow][acb] = AL.v[0];
    *(uint4*)&Al[arow][acb + 8] = AL.v[1];
    *(uint4*)&Bh[brow][bcb] = BH.v;
    *(uint4*)&Bl[brow][bcb] = BL.v;
    __syncthreads();

    bf16x8 ah[4], al[4], bh[2], bl[2];
#pragma unroll
    for (int mi = 0; mi < 4; ++mi) {
      int r = wr * 64 + mi * 16 + l15;
      ah[mi] = *(const bf16x8*)&Ah[r][quad * 8];
      al[mi] = *(const bf16x8*)&Al[r][quad * 8];
    }
#pragma unroll
    for (int ni = 0; ni < 2; ++ni) {
      int r = wc * 32 + ni * 16 + l15;
      bh[ni] = *(const bf16x8*)&Bh[r][quad * 8];
      bl[ni] = *(const bf16x8*)&Bl[r][quad * 8];
    }
#pragma unroll
    for (int mi = 0; mi < 4; ++mi)
#pragma unroll
      for (int ni = 0; ni < 2; ++ni) {
        acc[mi][ni] = __builtin_amdgcn_mfma_f32_16x16x32_bf16(ah[mi], bh[ni], acc[mi][ni], 0, 0, 0);
        acc[mi][ni] = __builtin_amdgcn_mfma_f32_16x16x32_bf16(al[mi], bh[ni], acc[mi][ni], 0, 0, 0);
        acc[mi][ni] = __builtin_amdgcn_mfma_f32_16x16x32_bf16(ah[mi], bl[ni], acc[mi][ni], 0, 0, 0);
      }
  }

#pragma unroll
  for (int mi = 0; mi < 4; ++mi)
#pragma unroll
    for (int ni = 0; ni < 2; ++ni) {
      int n = nblk + wc * 32 + ni * 16 + l15;
      float b = bd[n];
#pragma unroll
      for (int r = 0; r < 4; ++r) {
        int m = mblk + wr * 64 + mi * 16 + quad * 4 + r;
        if (m < N) h[(size_t)m * EMBED + n] = lrelu(acc[mi][ni][r] + b, 0.01f);
      }
    }
}

// ---------------------------------------------------------------------------
// K2 (MFMA split-bf16): g = h @ Wg^T, fused att-dot epilogue.
// ---------------------------------------------------------------------------
__global__ __launch_bounds__(256) void gemm2_mfma_kernel(
    const float* __restrict__ h, const float* __restrict__ Wg,
    const float* __restrict__ att_src, const float* __restrict__ att_dst,
    float* __restrict__ g, float* __restrict__ a_src, float* __restrict__ a_dst,
    int N) {
  __shared__ __align__(16) unsigned short Ah[128][LDA];
  __shared__ __align__(16) unsigned short Al[128][LDA];
  __shared__ __align__(16) unsigned short Bh[64][LDA];
  __shared__ __align__(16) unsigned short Bl[64][LDA];

  const int tid = threadIdx.x;
  const int lane = tid & 63;
  const int wid = tid >> 6;
  const int wr = wid >> 1, wc = wid & 1;
  const int mblk = blockIdx.x * 128;
  const int quad = lane >> 4;
  const int l15 = lane & 15;

  const int arow = tid >> 1, acb = (tid & 1) * 16;
  const int brow = tid >> 2, bcb = (tid & 3) * 8;
  const bool avalid = (mblk + arow) < N;
  const float* aptr = h + (size_t)(mblk + arow) * EMBED + acb;
  const float* bptr = Wg + (size_t)brow * EMBED + bcb;

  f32x4 acc[4][2];
#pragma unroll
  for (int i = 0; i < 4; ++i)
#pragma unroll
    for (int j = 0; j < 2; ++j) acc[i][j] = (f32x4){0.f, 0.f, 0.f, 0.f};

  for (int k0 = 0; k0 < EMBED; k0 += 32) {
    float4 t0, t1, t2, t3;
    if (avalid) {
      t0 = *(const float4*)(aptr + k0);
      t1 = *(const float4*)(aptr + k0 + 4);
      t2 = *(const float4*)(aptr + k0 + 8);
      t3 = *(const float4*)(aptr + k0 + 12);
    } else {
      t0 = t1 = t2 = t3 = make_float4(0.f, 0.f, 0.f, 0.f);
    }
    float4 u0 = *(const float4*)(bptr + k0);
    float4 u1 = *(const float4*)(bptr + k0 + 4);

    float av[16] = {t0.x, t0.y, t0.z, t0.w, t1.x, t1.y, t1.z, t1.w,
                    t2.x, t2.y, t2.z, t2.w, t3.x, t3.y, t3.z, t3.w};
    union { unsigned short us[16]; uint4 v[2]; } AH, AL;
#pragma unroll
    for (int i = 0; i < 16; ++i) {
      unsigned short hi = f2bf(av[i]);
      AH.us[i] = hi;
      AL.us[i] = f2bf(av[i] - bf2f(hi));
    }
    float bv[8] = {u0.x, u0.y, u0.z, u0.w, u1.x, u1.y, u1.z, u1.w};
    union { unsigned short us[8]; uint4 v; } BH, BL;
#pragma unroll
    for (int i = 0; i < 8; ++i) {
      unsigned short hi = f2bf(bv[i]);
      BH.us[i] = hi;
      BL.us[i] = f2bf(bv[i] - bf2f(hi));
    }

    __syncthreads();
    *(uint4*)&Ah[arow][acb] = AH.v[0];
    *(uint4*)&Ah[arow][acb + 8] = AH.v[1];
    *(uint4*)&Al[arow][acb] = AL.v[0];
    *(uint4*)&Al[arow][acb + 8] = AL.v[1];
    *(uint4*)&Bh[brow][bcb] = BH.v;
    *(uint4*)&Bl[brow][bcb] = BL.v;
    __syncthreads();

    bf16x8 ah[4], al[4], bh[2], bl[2];
#pragma unroll
    for (int mi = 0; mi < 4; ++mi) {
      int r = wr * 64 + mi * 16 + l15;
      ah[mi] = *(const bf16x8*)&Ah[r][quad * 8];
      al[mi] = *(const bf16x8*)&Al[r][quad * 8];
    }
#pragma unroll
    for (int ni = 0; ni < 2; ++ni) {
      int r = wc * 32 + ni * 16 + l15;
      bh[ni] = *(const bf16x8*)&Bh[r][quad * 8];
      bl[ni] = *(const bf16x8*)&Bl[r][quad * 8];
    }
#pragma unroll
    for (int mi = 0; mi < 4; ++mi)
#pragma unroll
      for (int ni = 0; ni < 2; ++ni) {
        acc[mi][ni] = __builtin_amdgcn_mfma_f32_16x16x32_bf16(ah[mi], bh[ni], acc[mi][ni], 0, 0, 0);
        acc[mi][ni] = __builtin_amdgcn_mfma_f32_16x16x32_bf16(al[mi], bh[ni], acc[mi][ni], 0, 0, 0);
        acc[mi][ni] = __builtin_amdgcn_mfma_f32_16x16x32_bf16(ah[mi], bl[ni], acc[mi][ni], 0, 0, 0);
      }
  }

  float as_[2], ad_[2];
#pragma unroll
  for (int ni = 0; ni < 2; ++ni) {
    int n = wc * 32 + ni * 16 + l15;
    as_[ni] = att_src[n];
    ad_[ni] = att_dst[n];
  }
#pragma unroll
  for (int mi = 0; mi < 4; ++mi) {
#pragma unroll
    for (int r = 0; r < 4; ++r) {
      int m = mblk + wr * 64 + mi * 16 + quad * 4 + r;
      float ps = acc[mi][0][r] * as_[0] + acc[mi][1][r] * as_[1];
      float pd = acc[mi][0][r] * ad_[0] + acc[mi][1][r] * ad_[1];
#pragma unroll
      for (int d = 1; d < 16; d <<= 1) {
        ps += __shfl_xor(ps, d, 64);
        pd += __shfl_xor(pd, d, 64);
      }
      if (m < N) {
#pragma unroll
        for (int ni = 0; ni < 2; ++ni) {
          int n = wc * 32 + ni * 16 + l15;
          g[(size_t)m * OUT_DIM + n] = acc[mi][ni][r];
        }
        if (l15 == 0 && wc == 0) {
          a_src[m] = ps;
          a_dst[m] = pd;
        }
      }
    }
  }
  __syncthreads();
#pragma unroll
  for (int mi = 0; mi < 4; ++mi) {
#pragma unroll
    for (int r = 0; r < 4; ++r) {
      int m = mblk + wr * 64 + mi * 16 + quad * 4 + r;
      float ps = acc[mi][0][r] * as_[0] + acc[mi][1][r] * as_[1];
      float pd = acc[mi][0][r] * ad_[0] + acc[mi][1][r] * ad_[1];
#pragma unroll
      for (int d = 1; d < 16; d <<= 1) {
        ps += __shfl_xor(ps, d, 64);
        pd += __shfl_xor(pd, d, 64);
      }
      if (m < N && l15 == 0 && wc == 1) {
        atomicAdd(&a_src[m], ps);
        atomicAdd(&a_dst[m], pd);
      }
    }
  }
}

// ---------------------------------------------------------------------------
// Edge phase (deterministic 3-step software write-combining bin):
//  1) hist_count: per-block per-bucket counts (LDS), coalesced row write.
//  2) alloc_scan: 1 block; bucket totals, exclusive scan, rewrite hist rows
//     into exact per-(block,bucket) global bases. Zero global atomics, exact.
//  3) bin: re-rank in LDS, store 4B recs to block-exclusive positions.
// ---------------------------------------------------------------------------
__global__ __launch_bounds__(256) void hist_count_kernel(
    const int* __restrict__ ei, int* __restrict__ hist, int E, int N) {
  __shared__ int cnt[NBPAD];
  const int t = threadIdx.x;
  cnt[t] = 0;
  __syncthreads();
  const int T = E + N;
  const int base = blockIdx.x << SEGSH;
#pragma unroll
  for (int q = 0; q < (1 << SEGSH) / 256; ++q) {
    int i = base + q * 256 + t;
    if (i < T) {
      int d = (i < E) ? ei[E + i] : (i - E);
      atomicAdd(&cnt[d >> 8], 1);
    }
  }
  __syncthreads();
  hist[blockIdx.x * NBPAD + t] = cnt[t];
}

__global__ __launch_bounds__(256) void alloc_scan_kernel(
    int* __restrict__ hist, int* __restrict__ bucket_base,
    int* __restrict__ bucket_tot, int* __restrict__ offsets, int nblkP,
    int NB, int N, int T) {
  __shared__ int sc[256];
  const int t = threadIdx.x;
  int tot = 0;
  for (int k = 0; k < nblkP; ++k) tot += hist[k * NBPAD + t];
  sc[t] = tot;
  __syncthreads();
  for (int dlt = 1; dlt < 256; dlt <<= 1) {
    int add = (t >= dlt) ? sc[t - dlt] : 0;
    __syncthreads();
    sc[t] += add;
    __syncthreads();
  }
  const int bb = sc[t] - tot;  // exclusive scan
  if (t < NB) {
    bucket_base[t] = bb;
    bucket_tot[t] = tot;
  }
  if (t == 0) offsets[N] = T;
  int run = bb;
  for (int k = 0; k < nblkP; ++k) {
    int c = hist[k * NBPAD + t];
    hist[k * NBPAD + t] = run;
    run += c;
  }
}

__global__ __launch_bounds__(256) void bin_kernel(
    const int* __restrict__ ei, const int* __restrict__ hist,
    int* __restrict__ stageB, int E, int N) {
  __shared__ int cnt[NBPAD];
  __shared__ int basev[NBPAD];
  const int t = threadIdx.x;
  cnt[t] = 0;
  basev[t] = hist[blockIdx.x * NBPAD + t];
  __syncthreads();
  const int T = E + N;
  const int base = blockIdx.x << SEGSH;
#pragma unroll
  for (int q = 0; q < (1 << SEGSH) / 256; ++q) {
    int i = base + q * 256 + t;
    if (i < T) {
      int s, d;
      if (i < E) {
        s = ei[i];
        d = ei[E + i];
      } else {
        s = d = i - E;
      }
      int b = d >> 8;
      int r = atomicAdd(&cnt[b], 1);
      stageB[basev[b] + r] = (s << 8) | (d & 255);
    }
  }
}

// Per-bucket CSR build: LDS counting sort + e computation + coalesced flush.
__global__ __launch_bounds__(256) void build_kernel(
    const int* __restrict__ stageB, const int* __restrict__ bucket_base,
    const int* __restrict__ bucket_tot, const float* __restrict__ a_src,
    const float* __restrict__ a_dst, int* __restrict__ offsets,
    int2* __restrict__ csr_pack, int N) {
  __shared__ int cnt[256];
  __shared__ int pre[256];
  __shared__ int cur[256];
  __shared__ int2 buf[CAP_LDS];
  const int b = blockIdx.x;
  const int t = threadIdx.x;
  const int base = bucket_base[b];
  const int tot = bucket_tot[b];
  cnt[t] = 0;
  __syncthreads();
  const int* sp = stageB + base;
  for (int i = t; i < tot; i += 256) atomicAdd(&cnt[sp[i] & 255], 1);
  __syncthreads();
  int v = cnt[t];
  pre[t] = v;
  __syncthreads();
  for (int dlt = 1; dlt < 256; dlt <<= 1) {
    int add = (t >= dlt) ? pre[t - dlt] : 0;
    __syncthreads();
    pre[t] += add;
    __syncthreads();
  }
  const int excl = pre[t] - v;
  cur[t] = excl;
  const int d_self = (b << 8) | t;
  if (d_self < N) offsets[d_self] = base + excl;
  __syncthreads();
  for (int i = t; i < tot; i += 256) {
    int rec = sp[i];
    int dl = rec & 255;
    int s = rec >> 8;
    float e = a_src[s] + a_dst[(b << 8) | dl];
    e = e > 0.f ? e : 0.2f * e;  // leaky_relu(0.2)
    int pos = atomicAdd(&cur[dl], 1);
    int2 r2 = make_int2(s, __float_as_int(e));
    if (pos < CAP_LDS)
      buf[pos] = r2;
    else
      csr_pack[base + pos] = r2;  // safety spill (statistically never)
  }
  __syncthreads();
  const int lim = min(tot, CAP_LDS);
  for (int i = t; i < lim; i += 256) csr_pack[base + i] = buf[i];
}

// ---------------------------------------------------------------------------
// one wave per node, lane = output dim; readlane-broadcast aggregation
// ---------------------------------------------------------------------------
__global__ __launch_bounds__(256) void aggregate_kernel(
    const int* __restrict__ offsets, const int2* __restrict__ csr_pack,
    const float* __restrict__ g, const float* __restrict__ b_gat,
    float* __restrict__ out, int N) {
  const int lane = threadIdx.x & 63;
  const int node = blockIdx.x * 4 + (threadIdx.x >> 6);
  if (node >= N) return;
  const int beg = offsets[node], end = offsets[node + 1];

  float m = -1e30f;
  for (int j = beg + lane; j < end; j += 64)
    m = fmaxf(m, __int_as_float(csr_pack[j].y));
#pragma unroll
  for (int d = 1; d < 64; d <<= 1) m = fmaxf(m, __shfl_xor(m, d, 64));

  float l = 0.f;
  for (int j = beg + lane; j < end; j += 64)
    l += __expf(__int_as_float(csr_pack[j].y) - m);
#pragma unroll
  for (int d = 1; d < 64; d <<= 1) l += __shfl_xor(l, d, 64);
  const float inv_l = 1.f / l;

  float acc0 = 0.f, acc1 = 0.f, acc2 = 0.f, acc3 = 0.f;
  for (int jb = beg; jb < end; jb += 64) {
    int j = jb + lane;
    float p = 0.f;
    int s = 0;
    if (j < end) {
      int2 rec = csr_pack[j];
      p = __expf(__int_as_float(rec.y) - m) * inv_l;
      s = rec.x;
    }
    const int cnt = min(64, end - jb);
    int jj = 0;
    for (; jj + 4 <= cnt; jj += 4) {
      int s0 = __builtin_amdgcn_readlane(s, jj);
      int s1 = __builtin_amdgcn_readlane(s, jj + 1);
      int s2 = __builtin_amdgcn_readlane(s, jj + 2);
      int s3 = __builtin_amdgcn_readlane(s, jj + 3);
      float p0 = readlane_f(p, jj);
      float p1 = readlane_f(p, jj + 1);
      float p2 = readlane_f(p, jj + 2);
      float p3 = readlane_f(p, jj + 3);
      acc0 += p0 * g[((size_t)s0 << 6) + lane];
      acc1 += p1 * g[((size_t)s1 << 6) + lane];
      acc2 += p2 * g[((size_t)s2 << 6) + lane];
      acc3 += p3 * g[((size_t)s3 << 6) + lane];
    }
    for (; jj < cnt; ++jj) {
      int s0 = __builtin_amdgcn_readlane(s, jj);
      float p0 = readlane_f(p, jj);
      acc0 += p0 * g[((size_t)s0 << 6) + lane];
    }
  }
  out[(size_t)node * OUT_DIM + lane] = (acc0 + acc1) + (acc2 + acc3) + b_gat[lane];
}

// ---------------------------------------------------------------------------
extern "C" void kernel_launch(void* const* d_in, const int* in_sizes, int n_in,
                              void* d_out, int out_size, void* d_ws, size_t ws_size,
                              hipStream_t stream) {
  const float* x = (const float*)d_in[0];
  const int* ei = (const int*)d_in[1];
  const float* Wd = (const float*)d_in[2];
  const float* bd = (const float*)d_in[3];
  const float* Wg = (const float*)d_in[4];
  const float* att_src = (const float*)d_in[5];
  const float* att_dst = (const float*)d_in[6];
  const float* bg = (const float*)d_in[7];
  float* out = (float*)d_out;

  const int N = in_sizes[0] / IN_DIM;
  const int E = in_sizes[1] / 2;
  const int T = E + N;
  const int NB = (N + 255) >> 8;                    // 196
  const int nblkP = (T + (1 << SEGSH) - 1) >> SEGSH;  // 404

  char* ws = (char*)d_ws;
  size_t off = 0;
  auto alloc = [&](size_t bytes) -> void* {
    void* p = ws + off;
    off += (bytes + 15) & ~(size_t)15;
    return p;
  };
  float* h = (float*)alloc((size_t)N * EMBED * 4);
  float* g = (float*)alloc((size_t)N * OUT_DIM * 4);
  float* a_src = (float*)alloc((size_t)N * 4);
  float* a_dst = (float*)alloc((size_t)N * 4);
  int* offsets = (int*)alloc((size_t)(N + 1) * 4);
  int* hist = (int*)alloc((size_t)nblkP * NBPAD * 4);
  int* bucket_base = (int*)alloc((size_t)NBPAD * 4);
  int* bucket_tot = (int*)alloc((size_t)NBPAD * 4);
  int* stageB = (int*)alloc((size_t)T * 4);
  int2* csr_pack = (int2*)alloc((size_t)T * 8);

  hipLaunchKernelGGL(gemm1_mfma_kernel, dim3((N + 127) / 128, 2), dim3(256), 0,
                     stream, x, Wd, bd, h, N);
  hipLaunchKernelGGL(gemm2_mfma_kernel, dim3((N + 127) / 128), dim3(256), 0,
                     stream, h, Wg, att_src, att_dst, g, a_src, a_dst, N);
  hipLaunchKernelGGL(hist_count_kernel, dim3(nblkP), dim3(256), 0, stream,
                     ei, hist, E, N);
  hipLaunchKernelGGL(alloc_scan_kernel, dim3(1), dim3(256), 0, stream,
                     hist, bucket_base, bucket_tot, offsets, nblkP, NB, N, T);
  hipLaunchKernelGGL(bin_kernel, dim3(nblkP), dim3(256), 0, stream,
                     ei, hist, stageB, E, N);
  hipLaunchKernelGGL(build_kernel, dim3(NB), dim3(256), 0, stream,
                     stageB, bucket_base, bucket_tot, a_src, a_dst, offsets,
                     csr_pack, N);
  hipLaunchKernelGGL(aggregate_kernel, dim3((N + 3) / 4), dim3(256), 0, stream,
                     offsets, csr_pack, g, bg, out, N);
}

// Round 9
// 322.137 us; speedup vs baseline: 1.2623x; 1.2623x over previous
//
#include <hip/hip_runtime.h>
#include <math.h>

#define IN_DIM 512
#define EMBED 128
#define OUT_DIM 64
#define NBPAD 256      // padded bucket count (actual NB = ceil(N/256) = 196)
#define SEGSH 12       // 4096 edges per bin block
#define CAP_LDS 10240  // build LDS capacity (mean 8430, +19 sigma)

typedef __attribute__((ext_vector_type(8))) short bf16x8;
typedef __attribute__((ext_vector_type(4))) float f32x4;

__device__ __forceinline__ float lrelu(float v, float s) { return v > 0.f ? v : v * s; }

__device__ __forceinline__ float readlane_f(float v, int l) {
  return __int_as_float(__builtin_amdgcn_readlane(__float_as_int(v), l));
}

__device__ __forceinline__ unsigned short f2bf(float f) {
  unsigned int u = __float_as_uint(f);
  u += 0x7fff + ((u >> 16) & 1);  // RTNE
  return (unsigned short)(u >> 16);
}
__device__ __forceinline__ float bf2f(unsigned short h) {
  return __uint_as_float(((unsigned int)h) << 16);
}

#define LDA 40  // bf16 LDS stride: b128 frag reads 2-way aliased = free (m136)

// ---------------------------------------------------------------------------
// K1 (MFMA split-bf16): h = leaky_relu(x @ Wd^T + bd, 0.01)
// ---------------------------------------------------------------------------
__global__ __launch_bounds__(256) void gemm1_mfma_kernel(
    const float* __restrict__ x, const float* __restrict__ Wd,
    const float* __restrict__ bd, float* __restrict__ h, int N) {
  __shared__ __align__(16) unsigned short Ah[128][LDA];
  __shared__ __align__(16) unsigned short Al[128][LDA];
  __shared__ __align__(16) unsigned short Bh[64][LDA];
  __shared__ __align__(16) unsigned short Bl[64][LDA];

  const int tid = threadIdx.x;
  const int lane = tid & 63;
  const int wid = tid >> 6;
  const int wr = wid >> 1, wc = wid & 1;
  const int mblk = blockIdx.x * 128;
  const int nblk = blockIdx.y * 64;
  const int quad = lane >> 4;
  const int l15 = lane & 15;

  const int arow = tid >> 1, acb = (tid & 1) * 16;
  const int brow = tid >> 2, bcb = (tid & 3) * 8;
  const bool avalid = (mblk + arow) < N;
  const float* aptr = x + (size_t)(mblk + arow) * IN_DIM + acb;
  const float* bptr = Wd + (size_t)(nblk + brow) * IN_DIM + bcb;

  f32x4 acc[4][2];
#pragma unroll
  for (int i = 0; i < 4; ++i)
#pragma unroll
    for (int j = 0; j < 2; ++j) acc[i][j] = (f32x4){0.f, 0.f, 0.f, 0.f};

  for (int k0 = 0; k0 < IN_DIM; k0 += 32) {
    float4 t0, t1, t2, t3;
    if (avalid) {
      t0 = *(const float4*)(aptr + k0);
      t1 = *(const float4*)(aptr + k0 + 4);
      t2 = *(const float4*)(aptr + k0 + 8);
      t3 = *(const float4*)(aptr + k0 + 12);
    } else {
      t0 = t1 = t2 = t3 = make_float4(0.f, 0.f, 0.f, 0.f);
    }
    float4 u0 = *(const float4*)(bptr + k0);
    float4 u1 = *(const float4*)(bptr + k0 + 4);

    float av[16] = {t0.x, t0.y, t0.z, t0.w, t1.x, t1.y, t1.z, t1.w,
                    t2.x, t2.y, t2.z, t2.w, t3.x, t3.y, t3.z, t3.w};
    union { unsigned short us[16]; uint4 v[2]; } AH, AL;
#pragma unroll
    for (int i = 0; i < 16; ++i) {
      unsigned short hi = f2bf(av[i]);
      AH.us[i] = hi;
      AL.us[i] = f2bf(av[i] - bf2f(hi));
    }
    float bv[8] = {u0.x, u0.y, u0.z, u0.w, u1.x, u1.y, u1.z, u1.w};
    union { unsigned short us[8]; uint4 v; } BH, BL;
#pragma unroll
    for (int i = 0; i < 8; ++i) {
      unsigned short hi = f2bf(bv[i]);
      BH.us[i] = hi;
      BL.us[i] = f2bf(bv[i] - bf2f(hi));
    }

    __syncthreads();
    *(uint4*)&Ah[arow][acb] = AH.v[0];
    *(uint4*)&Ah[arow][acb + 8] = AH.v[1];
    *(uint4*)&Al[arow][acb] = AL.v[0];
    *(uint4*)&Al[arow][acb + 8] = AL.v[1];
    *(uint4*)&Bh[brow][bcb] = BH.v;
    *(uint4*)&Bl[brow][bcb] = BL.v;
    __syncthreads();

    bf16x8 ah[4], al[4], bh[2], bl[2];
#pragma unroll
    for (int mi = 0; mi < 4; ++mi) {
      int r = wr * 64 + mi * 16 + l15;
      ah[mi] = *(const bf16x8*)&Ah[r][quad * 8];
      al[mi] = *(const bf16x8*)&Al[r][quad * 8];
    }
#pragma unroll
    for (int ni = 0; ni < 2; ++ni) {
      int r = wc * 32 + ni * 16 + l15;
      bh[ni] = *(const bf16x8*)&Bh[r][quad * 8];
      bl[ni] = *(const bf16x8*)&Bl[r][quad * 8];
    }
#pragma unroll
    for (int mi = 0; mi < 4; ++mi)
#pragma unroll
      for (int ni = 0; ni < 2; ++ni) {
        acc[mi][ni] = __builtin_amdgcn_mfma_f32_16x16x32_bf16(ah[mi], bh[ni], acc[mi][ni], 0, 0, 0);
        acc[mi][ni] = __builtin_amdgcn_mfma_f32_16x16x32_bf16(al[mi], bh[ni], acc[mi][ni], 0, 0, 0);
        acc[mi][ni] = __builtin_amdgcn_mfma_f32_16x16x32_bf16(ah[mi], bl[ni], acc[mi][ni], 0, 0, 0);
      }
  }

#pragma unroll
  for (int mi = 0; mi < 4; ++mi)
#pragma unroll
    for (int ni = 0; ni < 2; ++ni) {
      int n = nblk + wc * 32 + ni * 16 + l15;
      float b = bd[n];
#pragma unroll
      for (int r = 0; r < 4; ++r) {
        int m = mblk + wr * 64 + mi * 16 + quad * 4 + r;
        if (m < N) h[(size_t)m * EMBED + n] = lrelu(acc[mi][ni][r] + b, 0.01f);
      }
    }
}

// ---------------------------------------------------------------------------
// K2 (MFMA split-bf16): g = h @ Wg^T, fused att-dot epilogue.
// ---------------------------------------------------------------------------
__global__ __launch_bounds__(256) void gemm2_mfma_kernel(
    const float* __restrict__ h, const float* __restrict__ Wg,
    const float* __restrict__ att_src, const float* __restrict__ att_dst,
    float* __restrict__ g, float* __restrict__ a_src, float* __restrict__ a_dst,
    int N) {
  __shared__ __align__(16) unsigned short Ah[128][LDA];
  __shared__ __align__(16) unsigned short Al[128][LDA];
  __shared__ __align__(16) unsigned short Bh[64][LDA];
  __shared__ __align__(16) unsigned short Bl[64][LDA];

  const int tid = threadIdx.x;
  const int lane = tid & 63;
  const int wid = tid >> 6;
  const int wr = wid >> 1, wc = wid & 1;
  const int mblk = blockIdx.x * 128;
  const int quad = lane >> 4;
  const int l15 = lane & 15;

  const int arow = tid >> 1, acb = (tid & 1) * 16;
  const int brow = tid >> 2, bcb = (tid & 3) * 8;
  const bool avalid = (mblk + arow) < N;
  const float* aptr = h + (size_t)(mblk + arow) * EMBED + acb;
  const float* bptr = Wg + (size_t)brow * EMBED + bcb;

  f32x4 acc[4][2];
#pragma unroll
  for (int i = 0; i < 4; ++i)
#pragma unroll
    for (int j = 0; j < 2; ++j) acc[i][j] = (f32x4){0.f, 0.f, 0.f, 0.f};

  for (int k0 = 0; k0 < EMBED; k0 += 32) {
    float4 t0, t1, t2, t3;
    if (avalid) {
      t0 = *(const float4*)(aptr + k0);
      t1 = *(const float4*)(aptr + k0 + 4);
      t2 = *(const float4*)(aptr + k0 + 8);
      t3 = *(const float4*)(aptr + k0 + 12);
    } else {
      t0 = t1 = t2 = t3 = make_float4(0.f, 0.f, 0.f, 0.f);
    }
    float4 u0 = *(const float4*)(bptr + k0);
    float4 u1 = *(const float4*)(bptr + k0 + 4);

    float av[16] = {t0.x, t0.y, t0.z, t0.w, t1.x, t1.y, t1.z, t1.w,
                    t2.x, t2.y, t2.z, t2.w, t3.x, t3.y, t3.z, t3.w};
    union { unsigned short us[16]; uint4 v[2]; } AH, AL;
#pragma unroll
    for (int i = 0; i < 16; ++i) {
      unsigned short hi = f2bf(av[i]);
      AH.us[i] = hi;
      AL.us[i] = f2bf(av[i] - bf2f(hi));
    }
    float bv[8] = {u0.x, u0.y, u0.z, u0.w, u1.x, u1.y, u1.z, u1.w};
    union { unsigned short us[8]; uint4 v; } BH, BL;
#pragma unroll
    for (int i = 0; i < 8; ++i) {
      unsigned short hi = f2bf(bv[i]);
      BH.us[i] = hi;
      BL.us[i] = f2bf(bv[i] - bf2f(hi));
    }

    __syncthreads();
    *(uint4*)&Ah[arow][acb] = AH.v[0];
    *(uint4*)&Ah[arow][acb + 8] = AH.v[1];
    *(uint4*)&Al[arow][acb] = AL.v[0];
    *(uint4*)&Al[arow][acb + 8] = AL.v[1];
    *(uint4*)&Bh[brow][bcb] = BH.v;
    *(uint4*)&Bl[brow][bcb] = BL.v;
    __syncthreads();

    bf16x8 ah[4], al[4], bh[2], bl[2];
#pragma unroll
    for (int mi = 0; mi < 4; ++mi) {
      int r = wr * 64 + mi * 16 + l15;
      ah[mi] = *(const bf16x8*)&Ah[r][quad * 8];
      al[mi] = *(const bf16x8*)&Al[r][quad * 8];
    }
#pragma unroll
    for (int ni = 0; ni < 2; ++ni) {
      int r = wc * 32 + ni * 16 + l15;
      bh[ni] = *(const bf16x8*)&Bh[r][quad * 8];
      bl[ni] = *(const bf16x8*)&Bl[r][quad * 8];
    }
#pragma unroll
    for (int mi = 0; mi < 4; ++mi)
#pragma unroll
      for (int ni = 0; ni < 2; ++ni) {
        acc[mi][ni] = __builtin_amdgcn_mfma_f32_16x16x32_bf16(ah[mi], bh[ni], acc[mi][ni], 0, 0, 0);
        acc[mi][ni] = __builtin_amdgcn_mfma_f32_16x16x32_bf16(al[mi], bh[ni], acc[mi][ni], 0, 0, 0);
        acc[mi][ni] = __builtin_amdgcn_mfma_f32_16x16x32_bf16(ah[mi], bl[ni], acc[mi][ni], 0, 0, 0);
      }
  }

  float as_[2], ad_[2];
#pragma unroll
  for (int ni = 0; ni < 2; ++ni) {
    int n = wc * 32 + ni * 16 + l15;
    as_[ni] = att_src[n];
    ad_[ni] = att_dst[n];
  }
#pragma unroll
  for (int mi = 0; mi < 4; ++mi) {
#pragma unroll
    for (int r = 0; r < 4; ++r) {
      int m = mblk + wr * 64 + mi * 16 + quad * 4 + r;
      float ps = acc[mi][0][r] * as_[0] + acc[mi][1][r] * as_[1];
      float pd = acc[mi][0][r] * ad_[0] + acc[mi][1][r] * ad_[1];
#pragma unroll
      for (int d = 1; d < 16; d <<= 1) {
        ps += __shfl_xor(ps, d, 64);
        pd += __shfl_xor(pd, d, 64);
      }
      if (m < N) {
#pragma unroll
        for (int ni = 0; ni < 2; ++ni) {
          int n = wc * 32 + ni * 16 + l15;
          g[(size_t)m * OUT_DIM + n] = acc[mi][ni][r];
        }
        if (l15 == 0 && wc == 0) {
          a_src[m] = ps;
          a_dst[m] = pd;
        }
      }
    }
  }
  __syncthreads();
#pragma unroll
  for (int mi = 0; mi < 4; ++mi) {
#pragma unroll
    for (int r = 0; r < 4; ++r) {
      int m = mblk + wr * 64 + mi * 16 + quad * 4 + r;
      float ps = acc[mi][0][r] * as_[0] + acc[mi][1][r] * as_[1];
      float pd = acc[mi][0][r] * ad_[0] + acc[mi][1][r] * ad_[1];
#pragma unroll
      for (int d = 1; d < 16; d <<= 1) {
        ps += __shfl_xor(ps, d, 64);
        pd += __shfl_xor(pd, d, 64);
      }
      if (m < N && l15 == 0 && wc == 1) {
        atomicAdd(&a_src[m], ps);
        atomicAdd(&a_dst[m], pd);
      }
    }
  }
}

// ---------------------------------------------------------------------------
// Edge phase (deterministic software write-combining bin, parallel alloc):
//  1) hist_count: per-(edge-block,bucket) counts, stored TRANSPOSED:
//     histT[bucket][block] so each bucket's row is contiguous.
//  2) row_scan (256 blocks): exclusive scan each bucket row + row total.
//  3) base_scan (1 block, LDS only): exclusive scan of bucket totals.
//  4) bin: base = bucket_base[t] + histT[t][k]; block-exclusive stores.
// ---------------------------------------------------------------------------
__global__ __launch_bounds__(256) void hist_count_kernel(
    const int* __restrict__ ei, int* __restrict__ histT, int nblkP, int E,
    int N) {
  __shared__ int cnt[NBPAD];
  const int t = threadIdx.x;
  cnt[t] = 0;
  __syncthreads();
  const int T = E + N;
  const int base = blockIdx.x << SEGSH;
#pragma unroll
  for (int q = 0; q < (1 << SEGSH) / 256; ++q) {
    int i = base + q * 256 + t;
    if (i < T) {
      int d = (i < E) ? ei[E + i] : (i - E);
      atomicAdd(&cnt[d >> 8], 1);
    }
  }
  __syncthreads();
  histT[(size_t)t * nblkP + blockIdx.x] = cnt[t];
}

// one block per bucket: exclusive scan of histT row (nblkP elems), row total.
__global__ __launch_bounds__(256) void row_scan_kernel(
    int* __restrict__ histT, int* __restrict__ bucket_tot, int nblkP) {
  __shared__ int sc[256];
  const int t = threadIdx.x;
  int* row = histT + (size_t)blockIdx.x * nblkP;
  const int per = (nblkP + 255) / 256;
  int loc[8];  // per <= 8 supported (nblkP <= 2048)
  int sum = 0;
#pragma unroll 4
  for (int j = 0; j < per; ++j) {
    int idx = t * per + j;
    int v = (idx < nblkP) ? row[idx] : 0;
    loc[j] = sum;  // thread-local exclusive prefix
    sum += v;
  }
  sc[t] = sum;
  __syncthreads();
  for (int dlt = 1; dlt < 256; dlt <<= 1) {
    int add = (t >= dlt) ? sc[t - dlt] : 0;
    __syncthreads();
    sc[t] += add;
    __syncthreads();
  }
  const int off = sc[t] - sum;  // block-level exclusive prefix
#pragma unroll 4
  for (int j = 0; j < per; ++j) {
    int idx = t * per + j;
    if (idx < nblkP) row[idx] = off + loc[j];
  }
  if (t == 255) bucket_tot[blockIdx.x] = sc[255];
}

// 1 block: exclusive scan over NBPAD bucket totals (pure LDS, no serial
// global chain). Also writes offsets[N] = T.
__global__ __launch_bounds__(256) void base_scan_kernel(
    const int* __restrict__ bucket_tot, int* __restrict__ bucket_base,
    int* __restrict__ offsets, int N, int T) {
  __shared__ int sc[256];
  const int t = threadIdx.x;
  int v = bucket_tot[t];
  sc[t] = v;
  __syncthreads();
  for (int dlt = 1; dlt < 256; dlt <<= 1) {
    int add = (t >= dlt) ? sc[t - dlt] : 0;
    __syncthreads();
    sc[t] += add;
    __syncthreads();
  }
  bucket_base[t] = sc[t] - v;
  if (t == 0) offsets[N] = T;
}

__global__ __launch_bounds__(256) void bin_kernel(
    const int* __restrict__ ei, const int* __restrict__ histT,
    const int* __restrict__ bucket_base, int* __restrict__ stageB, int nblkP,
    int E, int N) {
  __shared__ int cnt[NBPAD];
  __shared__ int basev[NBPAD];
  const int t = threadIdx.x;
  cnt[t] = 0;
  basev[t] = bucket_base[t] + histT[(size_t)t * nblkP + blockIdx.x];
  __syncthreads();
  const int T = E + N;
  const int base = blockIdx.x << SEGSH;
#pragma unroll
  for (int q = 0; q < (1 << SEGSH) / 256; ++q) {
    int i = base + q * 256 + t;
    if (i < T) {
      int s, d;
      if (i < E) {
        s = ei[i];
        d = ei[E + i];
      } else {
        s = d = i - E;
      }
      int b = d >> 8;
      int r = atomicAdd(&cnt[b], 1);
      stageB[basev[b] + r] = (s << 8) | (d & 255);
    }
  }
}

// Per-bucket CSR build: LDS counting sort + e computation + coalesced flush.
__global__ __launch_bounds__(256) void build_kernel(
    const int* __restrict__ stageB, const int* __restrict__ bucket_base,
    const int* __restrict__ bucket_tot, const float* __restrict__ a_src,
    const float* __restrict__ a_dst, int* __restrict__ offsets,
    int2* __restrict__ csr_pack, int N) {
  __shared__ int cnt[256];
  __shared__ int pre[256];
  __shared__ int cur[256];
  __shared__ int2 buf[CAP_LDS];
  const int b = blockIdx.x;
  const int t = threadIdx.x;
  const int base = bucket_base[b];
  const int tot = bucket_tot[b];
  cnt[t] = 0;
  __syncthreads();
  const int* sp = stageB + base;
  for (int i = t; i < tot; i += 256) atomicAdd(&cnt[sp[i] & 255], 1);
  __syncthreads();
  int v = cnt[t];
  pre[t] = v;
  __syncthreads();
  for (int dlt = 1; dlt < 256; dlt <<= 1) {
    int add = (t >= dlt) ? pre[t - dlt] : 0;
    __syncthreads();
    pre[t] += add;
    __syncthreads();
  }
  const int excl = pre[t] - v;
  cur[t] = excl;
  const int d_self = (b << 8) | t;
  if (d_self < N) offsets[d_self] = base + excl;
  __syncthreads();
  for (int i = t; i < tot; i += 256) {
    int rec = sp[i];
    int dl = rec & 255;
    int s = rec >> 8;
    float e = a_src[s] + a_dst[(b << 8) | dl];
    e = e > 0.f ? e : 0.2f * e;  // leaky_relu(0.2)
    int pos = atomicAdd(&cur[dl], 1);
    int2 r2 = make_int2(s, __float_as_int(e));
    if (pos < CAP_LDS)
      buf[pos] = r2;
    else
      csr_pack[base + pos] = r2;  // safety spill (statistically never)
  }
  __syncthreads();
  const int lim = min(tot, CAP_LDS);
  for (int i = t; i < lim; i += 256) csr_pack[base + i] = buf[i];
}

// ---------------------------------------------------------------------------
// one wave per node, lane = output dim; readlane-broadcast aggregation
// ---------------------------------------------------------------------------
__global__ __launch_bounds__(256) void aggregate_kernel(
    const int* __restrict__ offsets, const int2* __restrict__ csr_pack,
    const float* __restrict__ g, const float* __restrict__ b_gat,
    float* __restrict__ out, int N) {
  const int lane = threadIdx.x & 63;
  const int node = blockIdx.x * 4 + (threadIdx.x >> 6);
  if (node >= N) return;
  const int beg = offsets[node], end = offsets[node + 1];

  float m = -1e30f;
  for (int j = beg + lane; j < end; j += 64)
    m = fmaxf(m, __int_as_float(csr_pack[j].y));
#pragma unroll
  for (int d = 1; d < 64; d <<= 1) m = fmaxf(m, __shfl_xor(m, d, 64));

  float l = 0.f;
  for (int j = beg + lane; j < end; j += 64)
    l += __expf(__int_as_float(csr_pack[j].y) - m);
#pragma unroll
  for (int d = 1; d < 64; d <<= 1) l += __shfl_xor(l, d, 64);
  const float inv_l = 1.f / l;

  float acc0 = 0.f, acc1 = 0.f, acc2 = 0.f, acc3 = 0.f;
  for (int jb = beg; jb < end; jb += 64) {
    int j = jb + lane;
    float p = 0.f;
    int s = 0;
    if (j < end) {
      int2 rec = csr_pack[j];
      p = __expf(__int_as_float(rec.y) - m) * inv_l;
      s = rec.x;
    }
    const int cnt = min(64, end - jb);
    int jj = 0;
    for (; jj + 4 <= cnt; jj += 4) {
      int s0 = __builtin_amdgcn_readlane(s, jj);
      int s1 = __builtin_amdgcn_readlane(s, jj + 1);
      int s2 = __builtin_amdgcn_readlane(s, jj + 2);
      int s3 = __builtin_amdgcn_readlane(s, jj + 3);
      float p0 = readlane_f(p, jj);
      float p1 = readlane_f(p, jj + 1);
      float p2 = readlane_f(p, jj + 2);
      float p3 = readlane_f(p, jj + 3);
      acc0 += p0 * g[((size_t)s0 << 6) + lane];
      acc1 += p1 * g[((size_t)s1 << 6) + lane];
      acc2 += p2 * g[((size_t)s2 << 6) + lane];
      acc3 += p3 * g[((size_t)s3 << 6) + lane];
    }
    for (; jj < cnt; ++jj) {
      int s0 = __builtin_amdgcn_readlane(s, jj);
      float p0 = readlane_f(p, jj);
      acc0 += p0 * g[((size_t)s0 << 6) + lane];
    }
  }
  out[(size_t)node * OUT_DIM + lane] = (acc0 + acc1) + (acc2 + acc3) + b_gat[lane];
}

// ---------------------------------------------------------------------------
extern "C" void kernel_launch(void* const* d_in, const int* in_sizes, int n_in,
                              void* d_out, int out_size, void* d_ws, size_t ws_size,
                              hipStream_t stream) {
  const float* x = (const float*)d_in[0];
  const int* ei = (const int*)d_in[1];
  const float* Wd = (const float*)d_in[2];
  const float* bd = (const float*)d_in[3];
  const float* Wg = (const float*)d_in[4];
  const float* att_src = (const float*)d_in[5];
  const float* att_dst = (const float*)d_in[6];
  const float* bg = (const float*)d_in[7];
  float* out = (float*)d_out;

  const int N = in_sizes[0] / IN_DIM;
  const int E = in_sizes[1] / 2;
  const int T = E + N;
  const int NB = (N + 255) >> 8;                       // 196
  const int nblkP = (T + (1 << SEGSH) - 1) >> SEGSH;   // ~415

  char* ws = (char*)d_ws;
  size_t off = 0;
  auto alloc = [&](size_t bytes) -> void* {
    void* p = ws + off;
    off += (bytes + 15) & ~(size_t)15;
    return p;
  };
  float* h = (float*)alloc((size_t)N * EMBED * 4);
  float* g = (float*)alloc((size_t)N * OUT_DIM * 4);
  float* a_src = (float*)alloc((size_t)N * 4);
  float* a_dst = (float*)alloc((size_t)N * 4);
  int* offsets = (int*)alloc((size_t)(N + 1) * 4);
  int* histT = (int*)alloc((size_t)NBPAD * nblkP * 4);
  int* bucket_base = (int*)alloc((size_t)NBPAD * 4);
  int* bucket_tot = (int*)alloc((size_t)NBPAD * 4);
  int* stageB = (int*)alloc((size_t)T * 4);
  int2* csr_pack = (int2*)alloc((size_t)T * 8);

  hipLaunchKernelGGL(gemm1_mfma_kernel, dim3((N + 127) / 128, 2), dim3(256), 0,
                     stream, x, Wd, bd, h, N);
  hipLaunchKernelGGL(gemm2_mfma_kernel, dim3((N + 127) / 128), dim3(256), 0,
                     stream, h, Wg, att_src, att_dst, g, a_src, a_dst, N);
  hipLaunchKernelGGL(hist_count_kernel, dim3(nblkP), dim3(256), 0, stream,
                     ei, histT, nblkP, E, N);
  hipLaunchKernelGGL(row_scan_kernel, dim3(NBPAD), dim3(256), 0, stream,
                     histT, bucket_tot, nblkP);
  hipLaunchKernelGGL(base_scan_kernel, dim3(1), dim3(256), 0, stream,
                     bucket_tot, bucket_base, offsets, N, T);
  hipLaunchKernelGGL(bin_kernel, dim3(nblkP), dim3(256), 0, stream,
                     ei, histT, bucket_base, stageB, nblkP, E, N);
  hipLaunchKernelGGL(build_kernel, dim3(NB), dim3(256), 0, stream,
                     stageB, bucket_base, bucket_tot, a_src, a_dst, offsets,
                     csr_pack, N);
  hipLaunchKernelGGL(aggregate_kernel, dim3((N + 3) / 4), dim3(256), 0, stream,
                     offsets, csr_pack, g, bg, out, N);
}

// Round 10
// 320.417 us; speedup vs baseline: 1.2690x; 1.0054x over previous
//
#include <hip/hip_runtime.h>
#include <math.h>

#define IN_DIM 512
#define EMBED 128
#define OUT_DIM 64
#define NBPAD 256      // padded bucket count (actual NB = ceil(N/256) = 196)
#define SEGSH 12       // 4096 edges per bin block
#define CAP_LDS 10240  // build LDS capacity (mean 8430, +19 sigma)

typedef __attribute__((ext_vector_type(8))) short bf16x8;
typedef __attribute__((ext_vector_type(4))) float f32x4;

__device__ __forceinline__ float lrelu(float v, float s) { return v > 0.f ? v : v * s; }

__device__ __forceinline__ float readlane_f(float v, int l) {
  return __int_as_float(__builtin_amdgcn_readlane(__float_as_int(v), l));
}

__device__ __forceinline__ unsigned short f2bf(float f) {
  unsigned int u = __float_as_uint(f);
  u += 0x7fff + ((u >> 16) & 1);  // RTNE
  return (unsigned short)(u >> 16);
}
__device__ __forceinline__ float bf2f(unsigned short h) {
  return __uint_as_float(((unsigned int)h) << 16);
}

#define LDA 40  // bf16 LDS stride: 16B-aligned rows; frag reads 2-way = free

// ---------------------------------------------------------------------------
// K1 (MFMA split-bf16): h = leaky_relu(x @ Wd^T + bd, 0.01)
// Register prefetch: iter k+1's global loads issue before iter k's MFMAs.
// ---------------------------------------------------------------------------
__global__ __launch_bounds__(256) void gemm1_mfma_kernel(
    const float* __restrict__ x, const float* __restrict__ Wd,
    const float* __restrict__ bd, float* __restrict__ h, int N) {
  __shared__ __align__(16) unsigned short Ah[128][LDA];
  __shared__ __align__(16) unsigned short Al[128][LDA];
  __shared__ __align__(16) unsigned short Bh[64][LDA];
  __shared__ __align__(16) unsigned short Bl[64][LDA];

  const int tid = threadIdx.x;
  const int lane = tid & 63;
  const int wid = tid >> 6;
  const int wr = wid >> 1, wc = wid & 1;
  const int mblk = blockIdx.x * 128;
  const int nblk = blockIdx.y * 64;
  const int quad = lane >> 4;
  const int l15 = lane & 15;

  const int arow = tid >> 1, acb = (tid & 1) * 16;
  const int brow = tid >> 2, bcb = (tid & 3) * 8;
  const bool avalid = (mblk + arow) < N;
  const float* aptr = x + (size_t)(mblk + arow) * IN_DIM + acb;
  const float* bptr = Wd + (size_t)(nblk + brow) * IN_DIM + bcb;

  f32x4 acc[4][2];
#pragma unroll
  for (int i = 0; i < 4; ++i)
#pragma unroll
    for (int j = 0; j < 2; ++j) acc[i][j] = (f32x4){0.f, 0.f, 0.f, 0.f};

  float4 t0, t1, t2, t3, u0, u1;
  auto do_load = [&](int k0) {
    if (avalid) {
      t0 = *(const float4*)(aptr + k0);
      t1 = *(const float4*)(aptr + k0 + 4);
      t2 = *(const float4*)(aptr + k0 + 8);
      t3 = *(const float4*)(aptr + k0 + 12);
    } else {
      t0 = t1 = t2 = t3 = make_float4(0.f, 0.f, 0.f, 0.f);
    }
    u0 = *(const float4*)(bptr + k0);
    u1 = *(const float4*)(bptr + k0 + 4);
  };
  do_load(0);

  for (int k0 = 0; k0 < IN_DIM; k0 += 32) {
    float av[16] = {t0.x, t0.y, t0.z, t0.w, t1.x, t1.y, t1.z, t1.w,
                    t2.x, t2.y, t2.z, t2.w, t3.x, t3.y, t3.z, t3.w};
    union { unsigned short us[16]; uint4 v[2]; } AH, AL;
#pragma unroll
    for (int i = 0; i < 16; ++i) {
      unsigned short hi = f2bf(av[i]);
      AH.us[i] = hi;
      AL.us[i] = f2bf(av[i] - bf2f(hi));
    }
    float bv[8] = {u0.x, u0.y, u0.z, u0.w, u1.x, u1.y, u1.z, u1.w};
    union { unsigned short us[8]; uint4 v; } BH, BL;
#pragma unroll
    for (int i = 0; i < 8; ++i) {
      unsigned short hi = f2bf(bv[i]);
      BH.us[i] = hi;
      BL.us[i] = f2bf(bv[i] - bf2f(hi));
    }

    __syncthreads();
    *(uint4*)&Ah[arow][acb] = AH.v[0];
    *(uint4*)&Ah[arow][acb + 8] = AH.v[1];
    *(uint4*)&Al[arow][acb] = AL.v[0];
    *(uint4*)&Al[arow][acb + 8] = AL.v[1];
    *(uint4*)&Bh[brow][bcb] = BH.v;
    *(uint4*)&Bl[brow][bcb] = BL.v;
    __syncthreads();

    if (k0 + 32 < IN_DIM) do_load(k0 + 32);  // in flight during ds_read+MFMA

    bf16x8 ah[4], al[4], bh[2], bl[2];
#pragma unroll
    for (int mi = 0; mi < 4; ++mi) {
      int r = wr * 64 + mi * 16 + l15;
      ah[mi] = *(const bf16x8*)&Ah[r][quad * 8];
      al[mi] = *(const bf16x8*)&Al[r][quad * 8];
    }
#pragma unroll
    for (int ni = 0; ni < 2; ++ni) {
      int r = wc * 32 + ni * 16 + l15;
      bh[ni] = *(const bf16x8*)&Bh[r][quad * 8];
      bl[ni] = *(const bf16x8*)&Bl[r][quad * 8];
    }
#pragma unroll
    for (int mi = 0; mi < 4; ++mi)
#pragma unroll
      for (int ni = 0; ni < 2; ++ni) {
        acc[mi][ni] = __builtin_amdgcn_mfma_f32_16x16x32_bf16(ah[mi], bh[ni], acc[mi][ni], 0, 0, 0);
        acc[mi][ni] = __builtin_amdgcn_mfma_f32_16x16x32_bf16(al[mi], bh[ni], acc[mi][ni], 0, 0, 0);
        acc[mi][ni] = __builtin_amdgcn_mfma_f32_16x16x32_bf16(ah[mi], bl[ni], acc[mi][ni], 0, 0, 0);
      }
  }

#pragma unroll
  for (int mi = 0; mi < 4; ++mi)
#pragma unroll
    for (int ni = 0; ni < 2; ++ni) {
      int n = nblk + wc * 32 + ni * 16 + l15;
      float b = bd[n];
#pragma unroll
      for (int r = 0; r < 4; ++r) {
        int m = mblk + wr * 64 + mi * 16 + quad * 4 + r;
        if (m < N) h[(size_t)m * EMBED + n] = lrelu(acc[mi][ni][r] + b, 0.01f);
      }
    }
}

// ---------------------------------------------------------------------------
// K2 (MFMA split-bf16): g = h @ Wg^T, fused att-dot epilogue. Same prefetch.
// ---------------------------------------------------------------------------
__global__ __launch_bounds__(256) void gemm2_mfma_kernel(
    const float* __restrict__ h, const float* __restrict__ Wg,
    const float* __restrict__ att_src, const float* __restrict__ att_dst,
    float* __restrict__ g, float* __restrict__ a_src, float* __restrict__ a_dst,
    int N) {
  __shared__ __align__(16) unsigned short Ah[128][LDA];
  __shared__ __align__(16) unsigned short Al[128][LDA];
  __shared__ __align__(16) unsigned short Bh[64][LDA];
  __shared__ __align__(16) unsigned short Bl[64][LDA];

  const int tid = threadIdx.x;
  const int lane = tid & 63;
  const int wid = tid >> 6;
  const int wr = wid >> 1, wc = wid & 1;
  const int mblk = blockIdx.x * 128;
  const int quad = lane >> 4;
  const int l15 = lane & 15;

  const int arow = tid >> 1, acb = (tid & 1) * 16;
  const int brow = tid >> 2, bcb = (tid & 3) * 8;
  const bool avalid = (mblk + arow) < N;
  const float* aptr = h + (size_t)(mblk + arow) * EMBED + acb;
  const float* bptr = Wg + (size_t)brow * EMBED + bcb;

  f32x4 acc[4][2];
#pragma unroll
  for (int i = 0; i < 4; ++i)
#pragma unroll
    for (int j = 0; j < 2; ++j) acc[i][j] = (f32x4){0.f, 0.f, 0.f, 0.f};

  float4 t0, t1, t2, t3, u0, u1;
  auto do_load = [&](int k0) {
    if (avalid) {
      t0 = *(const float4*)(aptr + k0);
      t1 = *(const float4*)(aptr + k0 + 4);
      t2 = *(const float4*)(aptr + k0 + 8);
      t3 = *(const float4*)(aptr + k0 + 12);
    } else {
      t0 = t1 = t2 = t3 = make_float4(0.f, 0.f, 0.f, 0.f);
    }
    u0 = *(const float4*)(bptr + k0);
    u1 = *(const float4*)(bptr + k0 + 4);
  };
  do_load(0);

  for (int k0 = 0; k0 < EMBED; k0 += 32) {
    float av[16] = {t0.x, t0.y, t0.z, t0.w, t1.x, t1.y, t1.z, t1.w,
                    t2.x, t2.y, t2.z, t2.w, t3.x, t3.y, t3.z, t3.w};
    union { unsigned short us[16]; uint4 v[2]; } AH, AL;
#pragma unroll
    for (int i = 0; i < 16; ++i) {
      unsigned short hi = f2bf(av[i]);
      AH.us[i] = hi;
      AL.us[i] = f2bf(av[i] - bf2f(hi));
    }
    float bv[8] = {u0.x, u0.y, u0.z, u0.w, u1.x, u1.y, u1.z, u1.w};
    union { unsigned short us[8]; uint4 v; } BH, BL;
#pragma unroll
    for (int i = 0; i < 8; ++i) {
      unsigned short hi = f2bf(bv[i]);
      BH.us[i] = hi;
      BL.us[i] = f2bf(bv[i] - bf2f(hi));
    }

    __syncthreads();
    *(uint4*)&Ah[arow][acb] = AH.v[0];
    *(uint4*)&Ah[arow][acb + 8] = AH.v[1];
    *(uint4*)&Al[arow][acb] = AL.v[0];
    *(uint4*)&Al[arow][acb + 8] = AL.v[1];
    *(uint4*)&Bh[brow][bcb] = BH.v;
    *(uint4*)&Bl[brow][bcb] = BL.v;
    __syncthreads();

    if (k0 + 32 < EMBED) do_load(k0 + 32);

    bf16x8 ah[4], al[4], bh[2], bl[2];
#pragma unroll
    for (int mi = 0; mi < 4; ++mi) {
      int r = wr * 64 + mi * 16 + l15;
      ah[mi] = *(const bf16x8*)&Ah[r][quad * 8];
      al[mi] = *(const bf16x8*)&Al[r][quad * 8];
    }
#pragma unroll
    for (int ni = 0; ni < 2; ++ni) {
      int r = wc * 32 + ni * 16 + l15;
      bh[ni] = *(const bf16x8*)&Bh[r][quad * 8];
      bl[ni] = *(const bf16x8*)&Bl[r][quad * 8];
    }
#pragma unroll
    for (int mi = 0; mi < 4; ++mi)
#pragma unroll
      for (int ni = 0; ni < 2; ++ni) {
        acc[mi][ni] = __builtin_amdgcn_mfma_f32_16x16x32_bf16(ah[mi], bh[ni], acc[mi][ni], 0, 0, 0);
        acc[mi][ni] = __builtin_amdgcn_mfma_f32_16x16x32_bf16(al[mi], bh[ni], acc[mi][ni], 0, 0, 0);
        acc[mi][ni] = __builtin_amdgcn_mfma_f32_16x16x32_bf16(ah[mi], bl[ni], acc[mi][ni], 0, 0, 0);
      }
  }

  float as_[2], ad_[2];
#pragma unroll
  for (int ni = 0; ni < 2; ++ni) {
    int n = wc * 32 + ni * 16 + l15;
    as_[ni] = att_src[n];
    ad_[ni] = att_dst[n];
  }
#pragma unroll
  for (int mi = 0; mi < 4; ++mi) {
#pragma unroll
    for (int r = 0; r < 4; ++r) {
      int m = mblk + wr * 64 + mi * 16 + quad * 4 + r;
      float ps = acc[mi][0][r] * as_[0] + acc[mi][1][r] * as_[1];
      float pd = acc[mi][0][r] * ad_[0] + acc[mi][1][r] * ad_[1];
#pragma unroll
      for (int d = 1; d < 16; d <<= 1) {
        ps += __shfl_xor(ps, d, 64);
        pd += __shfl_xor(pd, d, 64);
      }
      if (m < N) {
#pragma unroll
        for (int ni = 0; ni < 2; ++ni) {
          int n = wc * 32 + ni * 16 + l15;
          g[(size_t)m * OUT_DIM + n] = acc[mi][ni][r];
        }
        if (l15 == 0 && wc == 0) {
          a_src[m] = ps;
          a_dst[m] = pd;
        }
      }
    }
  }
  __syncthreads();
#pragma unroll
  for (int mi = 0; mi < 4; ++mi) {
#pragma unroll
    for (int r = 0; r < 4; ++r) {
      int m = mblk + wr * 64 + mi * 16 + quad * 4 + r;
      float ps = acc[mi][0][r] * as_[0] + acc[mi][1][r] * as_[1];
      float pd = acc[mi][0][r] * ad_[0] + acc[mi][1][r] * ad_[1];
#pragma unroll
      for (int d = 1; d < 16; d <<= 1) {
        ps += __shfl_xor(ps, d, 64);
        pd += __shfl_xor(pd, d, 64);
      }
      if (m < N && l15 == 0 && wc == 1) {
        atomicAdd(&a_src[m], ps);
        atomicAdd(&a_dst[m], pd);
      }
    }
  }
}

// ---------------------------------------------------------------------------
// Edge phase (deterministic software write-combining bin, parallel alloc)
// ---------------------------------------------------------------------------
__global__ __launch_bounds__(256) void hist_count_kernel(
    const int* __restrict__ ei, int* __restrict__ histT, int nblkP, int E,
    int N) {
  __shared__ int cnt[NBPAD];
  const int t = threadIdx.x;
  cnt[t] = 0;
  __syncthreads();
  const int T = E + N;
  const int base = blockIdx.x << SEGSH;
#pragma unroll
  for (int q = 0; q < (1 << SEGSH) / 256; ++q) {
    int i = base + q * 256 + t;
    if (i < T) {
      int d = (i < E) ? ei[E + i] : (i - E);
      atomicAdd(&cnt[d >> 8], 1);
    }
  }
  __syncthreads();
  histT[(size_t)t * nblkP + blockIdx.x] = cnt[t];
}

__global__ __launch_bounds__(256) void row_scan_kernel(
    int* __restrict__ histT, int* __restrict__ bucket_tot, int nblkP) {
  __shared__ int sc[256];
  const int t = threadIdx.x;
  int* row = histT + (size_t)blockIdx.x * nblkP;
  const int per = (nblkP + 255) / 256;
  int loc[8];
  int sum = 0;
#pragma unroll 4
  for (int j = 0; j < per; ++j) {
    int idx = t * per + j;
    int v = (idx < nblkP) ? row[idx] : 0;
    loc[j] = sum;
    sum += v;
  }
  sc[t] = sum;
  __syncthreads();
  for (int dlt = 1; dlt < 256; dlt <<= 1) {
    int add = (t >= dlt) ? sc[t - dlt] : 0;
    __syncthreads();
    sc[t] += add;
    __syncthreads();
  }
  const int off = sc[t] - sum;
#pragma unroll 4
  for (int j = 0; j < per; ++j) {
    int idx = t * per + j;
    if (idx < nblkP) row[idx] = off + loc[j];
  }
  if (t == 255) bucket_tot[blockIdx.x] = sc[255];
}

__global__ __launch_bounds__(256) void base_scan_kernel(
    const int* __restrict__ bucket_tot, int* __restrict__ bucket_base,
    int* __restrict__ offsets, int N, int T) {
  __shared__ int sc[256];
  const int t = threadIdx.x;
  int v = bucket_tot[t];
  sc[t] = v;
  __syncthreads();
  for (int dlt = 1; dlt < 256; dlt <<= 1) {
    int add = (t >= dlt) ? sc[t - dlt] : 0;
    __syncthreads();
    sc[t] += add;
    __syncthreads();
  }
  bucket_base[t] = sc[t] - v;
  if (t == 0) offsets[N] = T;
}

__global__ __launch_bounds__(256) void bin_kernel(
    const int* __restrict__ ei, const int* __restrict__ histT,
    const int* __restrict__ bucket_base, int* __restrict__ stageB, int nblkP,
    int E, int N) {
  __shared__ int cnt[NBPAD];
  __shared__ int basev[NBPAD];
  const int t = threadIdx.x;
  cnt[t] = 0;
  basev[t] = bucket_base[t] + histT[(size_t)t * nblkP + blockIdx.x];
  __syncthreads();
  const int T = E + N;
  const int base = blockIdx.x << SEGSH;
#pragma unroll
  for (int q = 0; q < (1 << SEGSH) / 256; ++q) {
    int i = base + q * 256 + t;
    if (i < T) {
      int s, d;
      if (i < E) {
        s = ei[i];
        d = ei[E + i];
      } else {
        s = d = i - E;
      }
      int b = d >> 8;
      int r = atomicAdd(&cnt[b], 1);
      stageB[basev[b] + r] = (s << 8) | (d & 255);
    }
  }
}

__global__ __launch_bounds__(256) void build_kernel(
    const int* __restrict__ stageB, const int* __restrict__ bucket_base,
    const int* __restrict__ bucket_tot, const float* __restrict__ a_src,
    const float* __restrict__ a_dst, int* __restrict__ offsets,
    int2* __restrict__ csr_pack, int N) {
  __shared__ int cnt[256];
  __shared__ int pre[256];
  __shared__ int cur[256];
  __shared__ int2 buf[CAP_LDS];
  const int b = blockIdx.x;
  const int t = threadIdx.x;
  const int base = bucket_base[b];
  const int tot = bucket_tot[b];
  cnt[t] = 0;
  __syncthreads();
  const int* sp = stageB + base;
  for (int i = t; i < tot; i += 256) atomicAdd(&cnt[sp[i] & 255], 1);
  __syncthreads();
  int v = cnt[t];
  pre[t] = v;
  __syncthreads();
  for (int dlt = 1; dlt < 256; dlt <<= 1) {
    int add = (t >= dlt) ? pre[t - dlt] : 0;
    __syncthreads();
    pre[t] += add;
    __syncthreads();
  }
  const int excl = pre[t] - v;
  cur[t] = excl;
  const int d_self = (b << 8) | t;
  if (d_self < N) offsets[d_self] = base + excl;
  __syncthreads();
  for (int i = t; i < tot; i += 256) {
    int rec = sp[i];
    int dl = rec & 255;
    int s = rec >> 8;
    float e = a_src[s] + a_dst[(b << 8) | dl];
    e = e > 0.f ? e : 0.2f * e;  // leaky_relu(0.2)
    int pos = atomicAdd(&cur[dl], 1);
    int2 r2 = make_int2(s, __float_as_int(e));
    if (pos < CAP_LDS)
      buf[pos] = r2;
    else
      csr_pack[base + pos] = r2;  // safety spill (statistically never)
  }
  __syncthreads();
  const int lim = min(tot, CAP_LDS);
  for (int i = t; i < lim; i += 256) csr_pack[base + i] = buf[i];
}

// ---------------------------------------------------------------------------
// one wave per node, lane = output dim; readlane-broadcast aggregation
// ---------------------------------------------------------------------------
__global__ __launch_bounds__(256) void aggregate_kernel(
    const int* __restrict__ offsets, const int2* __restrict__ csr_pack,
    const float* __restrict__ g, const float* __restrict__ b_gat,
    float* __restrict__ out, int N) {
  const int lane = threadIdx.x & 63;
  const int node = blockIdx.x * 4 + (threadIdx.x >> 6);
  if (node >= N) return;
  const int beg = offsets[node], end = offsets[node + 1];

  float m = -1e30f;
  for (int j = beg + lane; j < end; j += 64)
    m = fmaxf(m, __int_as_float(csr_pack[j].y));
#pragma unroll
  for (int d = 1; d < 64; d <<= 1) m = fmaxf(m, __shfl_xor(m, d, 64));

  float l = 0.f;
  for (int j = beg + lane; j < end; j += 64)
    l += __expf(__int_as_float(csr_pack[j].y) - m);
#pragma unroll
  for (int d = 1; d < 64; d <<= 1) l += __shfl_xor(l, d, 64);
  const float inv_l = 1.f / l;

  float acc0 = 0.f, acc1 = 0.f, acc2 = 0.f, acc3 = 0.f;
  for (int jb = beg; jb < end; jb += 64) {
    int j = jb + lane;
    float p = 0.f;
    int s = 0;
    if (j < end) {
      int2 rec = csr_pack[j];
      p = __expf(__int_as_float(rec.y) - m) * inv_l;
      s = rec.x;
    }
    const int cnt = min(64, end - jb);
    int jj = 0;
    for (; jj + 4 <= cnt; jj += 4) {
      int s0 = __builtin_amdgcn_readlane(s, jj);
      int s1 = __builtin_amdgcn_readlane(s, jj + 1);
      int s2 = __builtin_amdgcn_readlane(s, jj + 2);
      int s3 = __builtin_amdgcn_readlane(s, jj + 3);
      float p0 = readlane_f(p, jj);
      float p1 = readlane_f(p, jj + 1);
      float p2 = readlane_f(p, jj + 2);
      float p3 = readlane_f(p, jj + 3);
      acc0 += p0 * g[((size_t)s0 << 6) + lane];
      acc1 += p1 * g[((size_t)s1 << 6) + lane];
      acc2 += p2 * g[((size_t)s2 << 6) + lane];
      acc3 += p3 * g[((size_t)s3 << 6) + lane];
    }
    for (; jj < cnt; ++jj) {
      int s0 = __builtin_amdgcn_readlane(s, jj);
      float p0 = readlane_f(p, jj);
      acc0 += p0 * g[((size_t)s0 << 6) + lane];
    }
  }
  out[(size_t)node * OUT_DIM + lane] = (acc0 + acc1) + (acc2 + acc3) + b_gat[lane];
}

// ---------------------------------------------------------------------------
extern "C" void kernel_launch(void* const* d_in, const int* in_sizes, int n_in,
                              void* d_out, int out_size, void* d_ws, size_t ws_size,
                              hipStream_t stream) {
  const float* x = (const float*)d_in[0];
  const int* ei = (const int*)d_in[1];
  const float* Wd = (const float*)d_in[2];
  const float* bd = (const float*)d_in[3];
  const float* Wg = (const float*)d_in[4];
  const float* att_src = (const float*)d_in[5];
  const float* att_dst = (const float*)d_in[6];
  const float* bg = (const float*)d_in[7];
  float* out = (float*)d_out;

  const int N = in_sizes[0] / IN_DIM;
  const int E = in_sizes[1] / 2;
  const int T = E + N;
  const int NB = (N + 255) >> 8;                       // 196
  const int nblkP = (T + (1 << SEGSH) - 1) >> SEGSH;   // ~411

  char* ws = (char*)d_ws;
  size_t off = 0;
  auto alloc = [&](size_t bytes) -> void* {
    void* p = ws + off;
    off += (bytes + 15) & ~(size_t)15;
    return p;
  };
  float* h = (float*)alloc((size_t)N * EMBED * 4);
  float* g = (float*)alloc((size_t)N * OUT_DIM * 4);
  float* a_src = (float*)alloc((size_t)N * 4);
  float* a_dst = (float*)alloc((size_t)N * 4);
  int* offsets = (int*)alloc((size_t)(N + 1) * 4);
  int* histT = (int*)alloc((size_t)NBPAD * nblkP * 4);
  int* bucket_base = (int*)alloc((size_t)NBPAD * 4);
  int* bucket_tot = (int*)alloc((size_t)NBPAD * 4);
  int* stageB = (int*)alloc((size_t)T * 4);
  int2* csr_pack = (int2*)alloc((size_t)T * 8);

  hipLaunchKernelGGL(gemm1_mfma_kernel, dim3((N + 127) / 128, 2), dim3(256), 0,
                     stream, x, Wd, bd, h, N);
  hipLaunchKernelGGL(gemm2_mfma_kernel, dim3((N + 127) / 128), dim3(256), 0,
                     stream, h, Wg, att_src, att_dst, g, a_src, a_dst, N);
  hipLaunchKernelGGL(hist_count_kernel, dim3(nblkP), dim3(256), 0, stream,
                     ei, histT, nblkP, E, N);
  hipLaunchKernelGGL(row_scan_kernel, dim3(NBPAD), dim3(256), 0, stream,
                     histT, bucket_tot, nblkP);
  hipLaunchKernelGGL(base_scan_kernel, dim3(1), dim3(256), 0, stream,
                     bucket_tot, bucket_base, offsets, N, T);
  hipLaunchKernelGGL(bin_kernel, dim3(nblkP), dim3(256), 0, stream,
                     ei, histT, bucket_base, stageB, nblkP, E, N);
  hipLaunchKernelGGL(build_kernel, dim3(NB), dim3(256), 0, stream,
                     stageB, bucket_base, bucket_tot, a_src, a_dst, offsets,
                     csr_pack, N);
  hipLaunchKernelGGL(aggregate_kernel, dim3((N + 3) / 4), dim3(256), 0, stream,
                     offsets, csr_pack, g, bg, out, N);
}